// Round 4
// baseline (707.036 us; speedup 1.0000x reference)
//
#include <hip/hip_runtime.h>
#include <hip/hip_bf16.h>

#define N_NODES 8192
#define IN_FEAT 256
#define OUT_F   64
#define NHEAD   4
#define HF      256     // NHEAD*OUT_F
#define NEG     0.2f

typedef unsigned short u16;
typedef __attribute__((ext_vector_type(8))) short short8;   // 8 bf16 (4 VGPRs)
typedef __attribute__((ext_vector_type(4))) float f32x4;    // MFMA C/D

__device__ __forceinline__ float bf2f(u16 x) {
    union { unsigned int u; float f; } v; v.u = ((unsigned int)x) << 16; return v.f;
}
__device__ __forceinline__ u16 f2bf(float f) {
    union { unsigned int u; float f; } v; v.f = f;
    unsigned int r = v.u + 0x7FFFu + ((v.u >> 16) & 1u);  // RNE
    return (u16)(r >> 16);
}
__device__ __forceinline__ float leaky(float x) {
    return fmaxf(x, NEG * x);   // valid for 0 < NEG < 1
}

// ---------------------------------------------------------------------------
// K1: per 8 rows: suppT = (X@W)^T per head (bf16, o-major rows of length N),
//     f1/f2 head dots, proj = X@Pw^T + proj_b + bias -> straight into d_out.
//     W/PW loads register-double-buffered to overlap latency with the fma chain.
// ---------------------------------------------------------------------------
#define RPB 8
__global__ __launch_bounds__(256) void k_gemm(
    const float* __restrict__ inp,   // [N, 256]
    const float* __restrict__ W,     // [256, 256] (k-major rows)
    const float* __restrict__ U,     // [H*64] flat
    const float* __restrict__ V,     // [H*64] flat
    const float* __restrict__ Bias,  // [256]
    const float* __restrict__ PW,    // [256 out][256 in]
    const float* __restrict__ PB,    // [256]
    u16*   __restrict__ suppT,       // [256 (h*64+o)][N] bf16
    float* __restrict__ f1,          // [H][N]
    float* __restrict__ f2,          // [H][N]
    float* __restrict__ outp)        // [N][256]  proj + bias + proj_b
{
    __shared__ __align__(16) float in_lds[RPB][IN_FEAT];
    const int c  = threadIdx.x;            // output column 0..255
    const int n0 = blockIdx.x * RPB;

    #pragma unroll
    for (int r = 0; r < RPB; ++r)
        in_lds[r][c] = inp[(size_t)(n0 + r) * IN_FEAT + c];
    __syncthreads();

    float accs[RPB], accp[RPB];
    #pragma unroll
    for (int r = 0; r < RPB; ++r) { accs[r] = 0.f; accp[r] = 0.f; }
    const float* pwrow = PW + (size_t)c * IN_FEAT;
    const float* wp    = W + c;

    // prefetch k=0..3
    float4 pwc = *(const float4*)(pwrow);
    float  w0 = wp[0], w1 = wp[HF], w2 = wp[2 * HF], w3 = wp[3 * HF];

    for (int k = 0; k < IN_FEAT; k += 4) {
        float4 pwn; float wn0, wn1, wn2, wn3;
        const int kn = k + 4;
        if (kn < IN_FEAT) {                       // uniform branch
            pwn = *(const float4*)(pwrow + kn);
            wn0 = wp[(kn + 0) * HF]; wn1 = wp[(kn + 1) * HF];
            wn2 = wp[(kn + 2) * HF]; wn3 = wp[(kn + 3) * HF];
        }
        #pragma unroll
        for (int r = 0; r < RPB; ++r) {
            const float4 xv = *(const float4*)&in_lds[r][k];
            accs[r] = fmaf(xv.x, w0, accs[r]);
            accs[r] = fmaf(xv.y, w1, accs[r]);
            accs[r] = fmaf(xv.z, w2, accs[r]);
            accs[r] = fmaf(xv.w, w3, accs[r]);
            accp[r] = fmaf(xv.x, pwc.x, accp[r]);
            accp[r] = fmaf(xv.y, pwc.y, accp[r]);
            accp[r] = fmaf(xv.z, pwc.z, accp[r]);
            accp[r] = fmaf(xv.w, pwc.w, accp[r]);
        }
        pwc = pwn; w0 = wn0; w1 = wn1; w2 = wn2; w3 = wn3;
    }

    const int lane = c & 63;
    const int h = c >> 6;
    const float uv = U[c], vv = V[c];
    const float bb = Bias[c] + PB[c];

    // suppT row c, cols n0..n0+7: one 16-B store
    union { uint4 v; u16 s[8]; } sp;
    #pragma unroll
    for (int r = 0; r < RPB; ++r) sp.s[r] = f2bf(accs[r]);
    *(uint4*)(suppT + (size_t)c * N_NODES + n0) = sp.v;

    #pragma unroll
    for (int r = 0; r < RPB; ++r) {
        const int n = n0 + r;
        const float sv = accs[r];
        float s1 = sv * uv, s2 = sv * vv;
        #pragma unroll
        for (int mm = 32; mm > 0; mm >>= 1) {
            s1 += __shfl_xor(s1, mm);
            s2 += __shfl_xor(s2, mm);
        }
        if (lane == 0) {
            f1[h * N_NODES + n] = s1;
            f2[h * N_NODES + n] = s2;
        }
        outp[(size_t)n * HF + c] = accp[r] + bb;
    }
}

// ---------------------------------------------------------------------------
// K2: per-head global max of f1 (upper bound for softmax shift; leaky is
//     monotone so leaky(max f1 + f2_i) >= max over edges of leaky(f1_j+f2_i))
// ---------------------------------------------------------------------------
__global__ __launch_bounds__(256) void k_f1max(const float* __restrict__ f1,
                                               float* __restrict__ f1max) {
    __shared__ float red[256];
    const int h = blockIdx.x;
    float m = -1e30f;
    for (int j = threadIdx.x; j < N_NODES; j += 256)
        m = fmaxf(m, f1[h * N_NODES + j]);
    red[threadIdx.x] = m;
    __syncthreads();
    for (int s = 128; s > 0; s >>= 1) {
        if (threadIdx.x < s) red[threadIdx.x] = fmaxf(red[threadIdx.x], red[threadIdx.x + s]);
        __syncthreads();
    }
    if (threadIdx.x == 0) f1max[h] = red[0];
}

// ---------------------------------------------------------------------------
// K3: MFMA attention. One block per 16-row i-tile; wave w = head w.
//   Phase 1: bit-pack 16 adjacency rows into LDS flag bytes (1 bit per j).
//   Phase 2: flash j-loop, K=32/step: e-tile built in regs in MFMA A-layout
//     (A[m=lane&15][k=quad*8+jj]); B from suppT (o-major) -> one uint4 per
//     16-feat n-tile; 4x mfma_f32_16x16x32_bf16 per step.
//   C layout (verified): col=lane&15, row=quad*4+reg.
// ---------------------------------------------------------------------------
#define TI 16
__global__ __launch_bounds__(256) void k_attn_mfma(
    const float* __restrict__ adj,   // [N, N] fp32
    const u16* __restrict__ suppT,   // [256][N] bf16 (row = h*64+o)
    const float* __restrict__ f1,    // [H][N]
    const float* __restrict__ f2,    // [H][N]
    const float* __restrict__ f1max, // [H]
    float* __restrict__ out)         // [N][256] fp32: proj in, proj+attn out
{
    // flag bytes: abits[i][g] bit jj = (adj[i0+i][8g+jj] != 0).
    // row stride 1026 u16 -> consumer lanes (different i=col) hit distinct banks.
    __shared__ u16 abits[TI][1026];   // ~32.8 KB

    const int i0   = blockIdx.x * TI;
    const int tid  = threadIdx.x;
    const int wv   = tid >> 6;        // wave = head
    const int lane = tid & 63;
    const int col  = lane & 15;       // m (A) / n (B) / col (C)
    const int quad = lane >> 4;

    // ---- Phase 1: stage adjacency flags (wave wv does rows 4wv..4wv+3) ----
    #pragma unroll
    for (int rr = 0; rr < 4; ++rr) {
        const int r = (wv << 2) + rr;
        const float* ar = adj + (size_t)(i0 + r) * N_NODES;
        #pragma unroll 2
        for (int it = 0; it < 16; ++it) {
            const int j = it * 512 + lane * 8;
            const float4 a0 = *(const float4*)(ar + j);
            const float4 a1 = *(const float4*)(ar + j + 4);
            const unsigned v =
                (unsigned)(a0.x != 0.f)        | ((unsigned)(a0.y != 0.f) << 1) |
                ((unsigned)(a0.z != 0.f) << 2) | ((unsigned)(a0.w != 0.f) << 3) |
                ((unsigned)(a1.x != 0.f) << 4) | ((unsigned)(a1.y != 0.f) << 5) |
                ((unsigned)(a1.z != 0.f) << 6) | ((unsigned)(a1.w != 0.f) << 7);
            abits[r][it * 64 + lane] = (u16)v;
        }
    }
    __syncthreads();

    // ---- Phase 2: flash j-loop ----
    const int h = wv;
    const float* f1h = f1 + (size_t)h * N_NODES;
    const float f2i  = f2[(size_t)h * N_NODES + i0 + col];      // i = col
    const float mi   = leaky(f1max[h] + f2i);                   // >= row max
    // B rows for this lane's n-tiles: (h*64 + col + 16t)
    const u16* bp0 = suppT + (size_t)(h * 64 + col) * N_NODES;

    f32x4 acc[4];
    #pragma unroll
    for (int t = 0; t < 4; ++t) acc[t] = (f32x4){0.f, 0.f, 0.f, 0.f};
    float lsum = 0.f;

    #pragma unroll 2
    for (int jb = 0; jb < N_NODES; jb += 32) {
        const int jq = jb + (quad << 3);                        // this lane's j base
        const float4 fa = *(const float4*)(f1h + jq);
        const float4 fb = *(const float4*)(f1h + jq + 4);
        const unsigned bw = abits[col][(jb >> 3) + quad];       // 8 flag bits

        const float fj[8] = {fa.x, fa.y, fa.z, fa.w, fb.x, fb.y, fb.z, fb.w};
        union { short8 v; u16 s[8]; } af;
        #pragma unroll
        for (int jj = 0; jj < 8; ++jj) {
            const float ts = fj[jj] + f2i;
            const float lw = fmaxf(ts, NEG * ts);               // leaky
            const float e  = ((bw >> jj) & 1) ? __expf(lw - mi) : 0.f;
            const unsigned eb = __float_as_uint(e) >> 16;       // truncate (e>=0)
            af.s[jj] = (u16)eb;
            lsum += __uint_as_float(eb << 16);                  // consistent with MFMA
        }

        #pragma unroll
        for (int t = 0; t < 4; ++t) {
            union { uint4 v; short8 f; } bf;
            bf.v = *(const uint4*)(bp0 + (size_t)(t << 4) * N_NODES + jq);
            acc[t] = __builtin_amdgcn_mfma_f32_16x16x32_bf16(af.v, bf.f, acc[t], 0, 0, 0);
        }
    }

    // denominator: reduce over quads (each quad summed its own k-slice)
    lsum += __shfl_xor(lsum, 16);
    lsum += __shfl_xor(lsum, 32);   // now lane L holds lsum for i = L&15

    // ---- epilogue: divide + add onto proj in d_out ----
    #pragma unroll
    for (int reg = 0; reg < 4; ++reg) {
        const int irow = (quad << 2) + reg;                     // C-layout row
        const float inv = 1.f / __shfl(lsum, irow);
        float* op = out + (size_t)(i0 + irow) * HF + (h << 6) + col;
        #pragma unroll
        for (int t = 0; t < 4; ++t) op[t << 4] += acc[t][reg] * inv;
    }
}

// ---------------------------------------------------------------------------
extern "C" void kernel_launch(void* const* d_in, const int* in_sizes, int n_in,
                              void* d_out, int out_size, void* d_ws, size_t ws_size,
                              hipStream_t stream) {
    const float* inp  = (const float*)d_in[0];  // [8192,256]
    const float* adj  = (const float*)d_in[1];  // [8192,8192]
    const float* W    = (const float*)d_in[2];  // [256,256]
    const float* U    = (const float*)d_in[3];  // [4,64,1]
    const float* V    = (const float*)d_in[4];  // [4,64,1]
    const float* Bias = (const float*)d_in[5];  // [1,256]
    const float* PW   = (const float*)d_in[6];  // [256,256]
    const float* PB   = (const float*)d_in[7];  // [256]
    float* out = (float*)d_out;                 // [8192,256] fp32

    char* ws = (char*)d_ws;
    u16*   suppT = (u16*)(ws);                                   // 4 MiB
    float* f1    = (float*)(ws + (4u << 20));                    // 128 KiB
    float* f2    = (float*)(ws + (4u << 20) + (128u << 10));     // 128 KiB
    float* f1mx  = (float*)(ws + (4u << 20) + (256u << 10));     // 16 B

    k_gemm<<<N_NODES / RPB, 256, 0, stream>>>(inp, W, U, V, Bias, PW, PB,
                                              suppT, f1, f2, out);
    k_f1max<<<NHEAD, 256, 0, stream>>>(f1, f1mx);
    k_attn_mfma<<<N_NODES / TI, 256, 0, stream>>>(adj, suppT, f1, f2, f1mx, out);
}

// Round 5
// 655.957 us; speedup vs baseline: 1.0779x; 1.0779x over previous
//
#include <hip/hip_runtime.h>
#include <hip/hip_bf16.h>

#define N_NODES 8192
#define IN_FEAT 256
#define OUT_F   64
#define NHEAD   4
#define HF      256     // NHEAD*OUT_F
#define NEG     0.2f
#define SUPPT_LD 8224   // 8192 + 32: breaks 16KB power-of-2 stride camping

typedef unsigned short u16;
typedef __attribute__((ext_vector_type(8))) short short8;   // 8 bf16 (4 VGPRs)
typedef __attribute__((ext_vector_type(4))) float f32x4;    // MFMA C/D

__device__ __forceinline__ u16 f2bf(float f) {
    union { unsigned int u; float f; } v; v.f = f;
    unsigned int r = v.u + 0x7FFFu + ((v.u >> 16) & 1u);  // RNE
    return (u16)(r >> 16);
}
__device__ __forceinline__ float leaky(float x) {
    return fmaxf(x, NEG * x);   // valid for 0 < NEG < 1
}

// ---------------------------------------------------------------------------
// K1: per 8 rows: suppT = (X@W)^T (bf16, o-major, padded LD), f1/f2 dots,
//     proj = X@Pw^T + proj_b + bias -> straight into d_out. Also zeroes num.
// ---------------------------------------------------------------------------
#define RPB 8
__global__ __launch_bounds__(256) void k_gemm(
    const float* __restrict__ inp,   // [N, 256]
    const float* __restrict__ W,     // [256, 256] (k-major rows)
    const float* __restrict__ U,     // [H*64] flat
    const float* __restrict__ V,     // [H*64] flat
    const float* __restrict__ Bias,  // [256]
    const float* __restrict__ PW,    // [256 out][256 in]
    const float* __restrict__ PB,    // [256]
    u16*   __restrict__ suppT,       // [256 (h*64+o)][SUPPT_LD] bf16
    float* __restrict__ f1,          // [H][N]
    float* __restrict__ f2,          // [H][N]
    float* __restrict__ outp,        // [N][256]  proj + bias + proj_b
    float* __restrict__ num)         // [N][256]  zeroed here
{
    __shared__ __align__(16) float in_lds[RPB][IN_FEAT];
    const int c  = threadIdx.x;            // output column 0..255
    const int n0 = blockIdx.x * RPB;

    #pragma unroll
    for (int r = 0; r < RPB; ++r)
        in_lds[r][c] = inp[(size_t)(n0 + r) * IN_FEAT + c];
    __syncthreads();

    float accs[RPB], accp[RPB];
    #pragma unroll
    for (int r = 0; r < RPB; ++r) { accs[r] = 0.f; accp[r] = 0.f; }
    const float* pwrow = PW + (size_t)c * IN_FEAT;
    const float* wp    = W + c;

    // prefetch k=0..3
    float4 pwc = *(const float4*)(pwrow);
    float  w0 = wp[0], w1 = wp[HF], w2 = wp[2 * HF], w3 = wp[3 * HF];

    for (int k = 0; k < IN_FEAT; k += 4) {
        float4 pwn; float wn0, wn1, wn2, wn3;
        const int kn = k + 4;
        if (kn < IN_FEAT) {                       // uniform branch
            pwn = *(const float4*)(pwrow + kn);
            wn0 = wp[(kn + 0) * HF]; wn1 = wp[(kn + 1) * HF];
            wn2 = wp[(kn + 2) * HF]; wn3 = wp[(kn + 3) * HF];
        }
        #pragma unroll
        for (int r = 0; r < RPB; ++r) {
            const float4 xv = *(const float4*)&in_lds[r][k];
            accs[r] = fmaf(xv.x, w0, accs[r]);
            accs[r] = fmaf(xv.y, w1, accs[r]);
            accs[r] = fmaf(xv.z, w2, accs[r]);
            accs[r] = fmaf(xv.w, w3, accs[r]);
            accp[r] = fmaf(xv.x, pwc.x, accp[r]);
            accp[r] = fmaf(xv.y, pwc.y, accp[r]);
            accp[r] = fmaf(xv.z, pwc.z, accp[r]);
            accp[r] = fmaf(xv.w, pwc.w, accp[r]);
        }
        pwc = pwn; w0 = wn0; w1 = wn1; w2 = wn2; w3 = wn3;
    }

    const int lane = c & 63;
    const int h = c >> 6;
    const float uv = U[c], vv = V[c];
    const float bb = Bias[c] + PB[c];

    // suppT row c, cols n0..n0+7: one 16-B store (stride 16448 B, non-pow2)
    union { uint4 v; u16 s[8]; } sp;
    #pragma unroll
    for (int r = 0; r < RPB; ++r) sp.s[r] = f2bf(accs[r]);
    *(uint4*)(suppT + (size_t)c * SUPPT_LD + n0) = sp.v;

    #pragma unroll
    for (int r = 0; r < RPB; ++r) {
        const int n = n0 + r;
        const float sv = accs[r];
        float s1 = sv * uv, s2 = sv * vv;
        #pragma unroll
        for (int mm = 32; mm > 0; mm >>= 1) {
            s1 += __shfl_xor(s1, mm);
            s2 += __shfl_xor(s2, mm);
        }
        if (lane == 0) {
            f1[h * N_NODES + n] = s1;
            f2[h * N_NODES + n] = s2;
        }
        outp[(size_t)n * HF + c] = accp[r] + bb;
        num [(size_t)n * HF + c] = 0.f;
    }
}

// ---------------------------------------------------------------------------
// K2: per-head global max of f1 (softmax shift upper bound); zeroes lsumg.
// ---------------------------------------------------------------------------
__global__ __launch_bounds__(256) void k_f1max(const float* __restrict__ f1,
                                               float* __restrict__ f1max,
                                               float* __restrict__ lsumg) {
    __shared__ float red[256];
    const int h = blockIdx.x;
    float m = -1e30f;
    for (int j = threadIdx.x; j < N_NODES; j += 256) {
        m = fmaxf(m, f1[h * N_NODES + j]);
        lsumg[h * N_NODES + j] = 0.f;
    }
    red[threadIdx.x] = m;
    __syncthreads();
    for (int s = 128; s > 0; s >>= 1) {
        if (threadIdx.x < s) red[threadIdx.x] = fmaxf(red[threadIdx.x], red[threadIdx.x + s]);
        __syncthreads();
    }
    if (threadIdx.x == 0) f1max[h] = red[0];
}

// ---------------------------------------------------------------------------
// K3: MFMA attention, j-SPLIT into JC chunks for occupancy.
//   block = (i-tile, j-chunk); wave = head. Partial numerator -> atomicAdd
//   into num[], partial denominator -> atomicAdd into lsumg[]. Shift mi is
//   chunk-invariant so partials compose exactly.
// ---------------------------------------------------------------------------
#define TI 16
#define JC 4
#define JCHUNK (N_NODES / JC)      // 2048
#define NTILE  (N_NODES / TI)      // 512 i-tiles
__global__ __launch_bounds__(256, 8) void k_attn_mfma(
    const float* __restrict__ adj,   // [N, N] fp32
    const u16* __restrict__ suppT,   // [256][SUPPT_LD] bf16 (row = h*64+o)
    const float* __restrict__ f1,    // [H][N]
    const float* __restrict__ f2,    // [H][N]
    const float* __restrict__ f1max, // [H]
    float* __restrict__ num,         // [N][256] fp32 partial numerators
    float* __restrict__ lsumg)       // [H][N] fp32 partial denominators
{
    // flag bytes for this (i-tile, j-chunk): abits[i][g] bit jj = adj!=0
    __shared__ u16 abits[TI][258];   // ~8.3 KB

    // all XCDs work the same j-chunk at once -> suppT slice stays L2-hot
    const int jc   = blockIdx.x / NTILE;       // j-chunk
    const int i0   = (blockIdx.x % NTILE) * TI;
    const int jbase = jc * JCHUNK;
    const int tid  = threadIdx.x;
    const int wv   = tid >> 6;        // wave = head
    const int lane = tid & 63;
    const int col  = lane & 15;       // m (A) / n (B) / col (C)
    const int quad = lane >> 4;

    // ---- Phase 1: stage adjacency flags (wave wv does rows 4wv..4wv+3) ----
    #pragma unroll
    for (int rr = 0; rr < 4; ++rr) {
        const int r = (wv << 2) + rr;
        const float* ar = adj + (size_t)(i0 + r) * N_NODES + jbase;
        #pragma unroll
        for (int it = 0; it < JCHUNK / 512; ++it) {   // 4 passes
            const int j = it * 512 + lane * 8;
            const float4 a0 = *(const float4*)(ar + j);
            const float4 a1 = *(const float4*)(ar + j + 4);
            const unsigned v =
                (unsigned)(a0.x != 0.f)        | ((unsigned)(a0.y != 0.f) << 1) |
                ((unsigned)(a0.z != 0.f) << 2) | ((unsigned)(a0.w != 0.f) << 3) |
                ((unsigned)(a1.x != 0.f) << 4) | ((unsigned)(a1.y != 0.f) << 5) |
                ((unsigned)(a1.z != 0.f) << 6) | ((unsigned)(a1.w != 0.f) << 7);
            abits[r][it * 64 + lane] = (u16)v;
        }
    }
    __syncthreads();

    // ---- Phase 2: flash j-loop over this chunk ----
    const int h = wv;
    const float* f1h = f1 + (size_t)h * N_NODES;
    const float f2i  = f2[(size_t)h * N_NODES + i0 + col];      // i = col
    const float mi   = leaky(f1max[h] + f2i);                   // >= row max
    const u16* bp0 = suppT + (size_t)(h * 64 + col) * SUPPT_LD + jbase;

    f32x4 acc[4];
    #pragma unroll
    for (int t = 0; t < 4; ++t) acc[t] = (f32x4){0.f, 0.f, 0.f, 0.f};
    float lsum = 0.f;

    for (int jl = 0; jl < JCHUNK; jl += 32) {
        const int jq = jl + (quad << 3);                        // chunk-local j
        const float4 fa = *(const float4*)(f1h + jbase + jq);
        const float4 fb = *(const float4*)(f1h + jbase + jq + 4);
        const unsigned bw = abits[col][(jl >> 3) + quad];       // 8 flag bits

        const float fj[8] = {fa.x, fa.y, fa.z, fa.w, fb.x, fb.y, fb.z, fb.w};
        union { short8 v; u16 s[8]; } af;
        #pragma unroll
        for (int jj = 0; jj < 8; ++jj) {
            const float ts = fj[jj] + f2i;
            const float lw = fmaxf(ts, NEG * ts);               // leaky
            const float e  = ((bw >> jj) & 1) ? __expf(lw - mi) : 0.f;
            const unsigned eb = __float_as_uint(e) >> 16;       // truncate (e>=0)
            af.s[jj] = (u16)eb;
            lsum += __uint_as_float(eb << 16);                  // consistent with MFMA
        }

        #pragma unroll
        for (int t = 0; t < 4; ++t) {
            union { uint4 v; short8 f; } bf;
            bf.v = *(const uint4*)(bp0 + (size_t)(t << 4) * SUPPT_LD + jq);
            acc[t] = __builtin_amdgcn_mfma_f32_16x16x32_bf16(af.v, bf.f, acc[t], 0, 0, 0);
        }
    }

    // partial denominator: reduce over quads, one atomic per i per wave
    lsum += __shfl_xor(lsum, 16);
    lsum += __shfl_xor(lsum, 32);   // lane L holds chunk-sum for i = L&15
    if (lane < 16) atomicAdd(&lsumg[h * N_NODES + i0 + lane], lsum);

    // partial numerator: atomicAdd in C layout (col=lane&15, row=quad*4+reg)
    #pragma unroll
    for (int reg = 0; reg < 4; ++reg) {
        const int irow = (quad << 2) + reg;
        float* op = num + (size_t)(i0 + irow) * HF + (h << 6) + col;
        #pragma unroll
        for (int t = 0; t < 4; ++t) atomicAdd(op + (t << 4), acc[t][reg]);
    }
}

// ---------------------------------------------------------------------------
// K4: out += num / lsum   (proj already sits in out from K1)
// ---------------------------------------------------------------------------
__global__ __launch_bounds__(256) void k_final(
    const float* __restrict__ num,   // [N][256]
    const float* __restrict__ lsumg, // [H][N]
    float* __restrict__ out)         // [N][256]
{
    const int idx = blockIdx.x * 256 + threadIdx.x;
    const int i = idx >> 8, c = idx & 255, h = c >> 6;
    out[idx] += num[idx] / lsumg[h * N_NODES + i];
}

// ---------------------------------------------------------------------------
extern "C" void kernel_launch(void* const* d_in, const int* in_sizes, int n_in,
                              void* d_out, int out_size, void* d_ws, size_t ws_size,
                              hipStream_t stream) {
    const float* inp  = (const float*)d_in[0];  // [8192,256]
    const float* adj  = (const float*)d_in[1];  // [8192,8192]
    const float* W    = (const float*)d_in[2];  // [256,256]
    const float* U    = (const float*)d_in[3];  // [4,64,1]
    const float* V    = (const float*)d_in[4];  // [4,64,1]
    const float* Bias = (const float*)d_in[5];  // [1,256]
    const float* PW   = (const float*)d_in[6];  // [256,256]
    const float* PB   = (const float*)d_in[7];  // [256]
    float* out = (float*)d_out;                 // [8192,256] fp32

    char* ws = (char*)d_ws;
    size_t off = 0;
    u16*   suppT = (u16*)(ws + off);   off += (size_t)HF * SUPPT_LD * 2;    // 4.21 MiB
    float* f1    = (float*)(ws + off); off += (size_t)NHEAD * N_NODES * 4;  // 128 KiB
    float* f2    = (float*)(ws + off); off += (size_t)NHEAD * N_NODES * 4;  // 128 KiB
    float* f1mx  = (float*)(ws + off); off += 256;
    float* lsumg = (float*)(ws + off); off += (size_t)NHEAD * N_NODES * 4;  // 128 KiB
    float* num   = (float*)(ws + off); off += (size_t)N_NODES * HF * 4;     // 8 MiB
    // total ws use ~12.6 MiB

    k_gemm<<<N_NODES / RPB, 256, 0, stream>>>(inp, W, U, V, Bias, PW, PB,
                                              suppT, f1, f2, out, num);
    k_f1max<<<NHEAD, 256, 0, stream>>>(f1, f1mx, lsumg);
    k_attn_mfma<<<NTILE * JC, 256, 0, stream>>>(adj, suppT, f1, f2, f1mx, num, lsumg);
    k_final<<<(N_NODES * HF) / 256, 256, 0, stream>>>(num, lsumg, out);
}

// Round 6
// 635.490 us; speedup vs baseline: 1.1126x; 1.0322x over previous
//
#include <hip/hip_runtime.h>
#include <hip/hip_bf16.h>

#define N_NODES 8192
#define IN_FEAT 256
#define OUT_F   64
#define NHEAD   4
#define HF      256     // NHEAD*OUT_F
#define NEG     0.2f
#define SUPPT_LD 8224   // 8192 + 32: breaks 16KB power-of-2 stride camping

typedef unsigned short u16;
typedef __attribute__((ext_vector_type(8))) short short8;   // 8 bf16 (4 VGPRs)
typedef __attribute__((ext_vector_type(4))) float f32x4;    // MFMA C/D

__device__ __forceinline__ u16 f2bf(float f) {
    union { unsigned int u; float f; } v; v.f = f;
    unsigned int r = v.u + 0x7FFFu + ((v.u >> 16) & 1u);  // RNE
    return (u16)(r >> 16);
}
__device__ __forceinline__ float leaky(float x) {
    return fmaxf(x, NEG * x);   // valid for 0 < NEG < 1
}

// ---------------------------------------------------------------------------
// K1: per 8 rows: suppT = (X@W)^T (bf16, o-major, padded LD), f1/f2 dots,
//     proj = X@Pw^T + proj_b + bias -> straight into d_out. Also zeroes num.
// ---------------------------------------------------------------------------
#define RPB 8
__global__ __launch_bounds__(256) void k_gemm(
    const float* __restrict__ inp,   // [N, 256]
    const float* __restrict__ W,     // [256, 256] (k-major rows)
    const float* __restrict__ U,     // [H*64] flat
    const float* __restrict__ V,     // [H*64] flat
    const float* __restrict__ Bias,  // [256]
    const float* __restrict__ PW,    // [256 out][256 in]
    const float* __restrict__ PB,    // [256]
    u16*   __restrict__ suppT,       // [256 (h*64+o)][SUPPT_LD] bf16
    float* __restrict__ f1,          // [H][N]
    float* __restrict__ f2,          // [H][N]
    float* __restrict__ outp,        // [N][256]  proj + bias + proj_b
    float* __restrict__ num)         // [N][256]  zeroed here
{
    __shared__ __align__(16) float in_lds[RPB][IN_FEAT];
    const int c  = threadIdx.x;            // output column 0..255
    const int n0 = blockIdx.x * RPB;

    #pragma unroll
    for (int r = 0; r < RPB; ++r)
        in_lds[r][c] = inp[(size_t)(n0 + r) * IN_FEAT + c];
    __syncthreads();

    float accs[RPB], accp[RPB];
    #pragma unroll
    for (int r = 0; r < RPB; ++r) { accs[r] = 0.f; accp[r] = 0.f; }
    const float* pwrow = PW + (size_t)c * IN_FEAT;
    const float* wp    = W + c;

    // prefetch k=0..3
    float4 pwc = *(const float4*)(pwrow);
    float  w0 = wp[0], w1 = wp[HF], w2 = wp[2 * HF], w3 = wp[3 * HF];

    for (int k = 0; k < IN_FEAT; k += 4) {
        float4 pwn; float wn0, wn1, wn2, wn3;
        const int kn = k + 4;
        if (kn < IN_FEAT) {                       // uniform branch
            pwn = *(const float4*)(pwrow + kn);
            wn0 = wp[(kn + 0) * HF]; wn1 = wp[(kn + 1) * HF];
            wn2 = wp[(kn + 2) * HF]; wn3 = wp[(kn + 3) * HF];
        }
        #pragma unroll
        for (int r = 0; r < RPB; ++r) {
            const float4 xv = *(const float4*)&in_lds[r][k];
            accs[r] = fmaf(xv.x, w0, accs[r]);
            accs[r] = fmaf(xv.y, w1, accs[r]);
            accs[r] = fmaf(xv.z, w2, accs[r]);
            accs[r] = fmaf(xv.w, w3, accs[r]);
            accp[r] = fmaf(xv.x, pwc.x, accp[r]);
            accp[r] = fmaf(xv.y, pwc.y, accp[r]);
            accp[r] = fmaf(xv.z, pwc.z, accp[r]);
            accp[r] = fmaf(xv.w, pwc.w, accp[r]);
        }
        pwc = pwn; w0 = wn0; w1 = wn1; w2 = wn2; w3 = wn3;
    }

    const int lane = c & 63;
    const int h = c >> 6;
    const float uv = U[c], vv = V[c];
    const float bb = Bias[c] + PB[c];

    // suppT row c, cols n0..n0+7: one 16-B store (stride 16448 B, non-pow2)
    union { uint4 v; u16 s[8]; } sp;
    #pragma unroll
    for (int r = 0; r < RPB; ++r) sp.s[r] = f2bf(accs[r]);
    *(uint4*)(suppT + (size_t)c * SUPPT_LD + n0) = sp.v;

    #pragma unroll
    for (int r = 0; r < RPB; ++r) {
        const int n = n0 + r;
        const float sv = accs[r];
        float s1 = sv * uv, s2 = sv * vv;
        #pragma unroll
        for (int mm = 32; mm > 0; mm >>= 1) {
            s1 += __shfl_xor(s1, mm);
            s2 += __shfl_xor(s2, mm);
        }
        if (lane == 0) {
            f1[h * N_NODES + n] = s1;
            f2[h * N_NODES + n] = s2;
        }
        outp[(size_t)n * HF + c] = accp[r] + bb;
        num [(size_t)n * HF + c] = 0.f;
    }
}

// ---------------------------------------------------------------------------
// K2: per-head global max of f1 (softmax shift upper bound); zeroes lsumg.
// ---------------------------------------------------------------------------
__global__ __launch_bounds__(256) void k_f1max(const float* __restrict__ f1,
                                               float* __restrict__ f1max,
                                               float* __restrict__ lsumg) {
    __shared__ float red[256];
    const int h = blockIdx.x;
    float m = -1e30f;
    for (int j = threadIdx.x; j < N_NODES; j += 256) {
        m = fmaxf(m, f1[h * N_NODES + j]);
        lsumg[h * N_NODES + j] = 0.f;
    }
    red[threadIdx.x] = m;
    __syncthreads();
    for (int s = 128; s > 0; s >>= 1) {
        if (threadIdx.x < s) red[threadIdx.x] = fmaxf(red[threadIdx.x], red[threadIdx.x + s]);
        __syncthreads();
    }
    if (threadIdx.x == 0) f1max[h] = red[0];
}

// ---------------------------------------------------------------------------
// K3: MFMA attention, j-split (JC chunks), 1-step software pipeline.
//   block = (i-tile, j-chunk); wave = head. Partial numerator -> atomicAdd
//   into num[], partial denominator -> atomicAdd into lsumg[]. Shift mi is
//   chunk-invariant so partials compose exactly.
//   NOTE: prefetch of the step past the chunk end reads garbage from the
//   adjacent ws buffers (in-bounds of d_ws) and is never consumed.
// ---------------------------------------------------------------------------
#define TI 16
#define JC 4
#define JCHUNK (N_NODES / JC)      // 2048
#define NTILE  (N_NODES / TI)      // 512 i-tiles
#define LOG2E  1.442695041f

__global__ __launch_bounds__(256, 4) void k_attn_mfma(
    const float* __restrict__ adj,   // [N, N] fp32
    const u16* __restrict__ suppT,   // [256][SUPPT_LD] bf16 (row = h*64+o)
    const float* __restrict__ f1,    // [H][N]
    const float* __restrict__ f2,    // [H][N]
    const float* __restrict__ f1max, // [H]
    float* __restrict__ num,         // [N][256] fp32 partial numerators
    float* __restrict__ lsumg)       // [H][N] fp32 partial denominators
{
    // flag bytes: abits[i][g] bit jj = (adj[i0+i][jbase+8g+jj] != 0). +4 pad
    // so the one-step-ahead prefetch stays in-bounds.
    __shared__ u16 abits[TI][260];   // ~8.3 KB

    const int jc    = blockIdx.x / NTILE;       // j-chunk
    const int i0    = (blockIdx.x % NTILE) * TI;
    const int jbase = jc * JCHUNK;
    const int tid   = threadIdx.x;
    const int wv    = tid >> 6;       // wave = head
    const int lane  = tid & 63;
    const int col   = lane & 15;      // m (A) / n (B) / col (C)
    const int quad  = lane >> 4;

    // ---- Phase 1: stage adjacency flags (wave wv does rows 4wv..4wv+3) ----
    #pragma unroll
    for (int rr = 0; rr < 4; ++rr) {
        const int r = (wv << 2) + rr;
        const float* ar = adj + (size_t)(i0 + r) * N_NODES + jbase;
        #pragma unroll
        for (int it = 0; it < JCHUNK / 512; ++it) {   // 4 passes
            const int j = it * 512 + lane * 8;
            const float4 a0 = *(const float4*)(ar + j);
            const float4 a1 = *(const float4*)(ar + j + 4);
            const unsigned v =
                (unsigned)(a0.x != 0.f)        | ((unsigned)(a0.y != 0.f) << 1) |
                ((unsigned)(a0.z != 0.f) << 2) | ((unsigned)(a0.w != 0.f) << 3) |
                ((unsigned)(a1.x != 0.f) << 4) | ((unsigned)(a1.y != 0.f) << 5) |
                ((unsigned)(a1.z != 0.f) << 6) | ((unsigned)(a1.w != 0.f) << 7);
            abits[r][it * 64 + lane] = (u16)v;
        }
    }
    __syncthreads();

    // ---- Phase 2: pipelined flash j-loop over this chunk ----
    const int h = wv;
    const float* f1p = f1 + (size_t)h * N_NODES + jbase + (quad << 3);
    const float f2i  = f2[(size_t)h * N_NODES + i0 + col];      // i = col
    const float mi   = leaky(f1max[h] + f2i);                   // >= row max
    const float mi1  = LOG2E * mi;
    const u16* bp0 = suppT + (size_t)(h * 64 + col) * SUPPT_LD + jbase + (quad << 3);

    f32x4 acc[4];
    #pragma unroll
    for (int t = 0; t < 4; ++t) acc[t] = (f32x4){0.f, 0.f, 0.f, 0.f};
    float lsum = 0.f;

    // prefetch step 0
    float4   fa_c = *(const float4*)(f1p);
    float4   fb_c = *(const float4*)(f1p + 4);
    unsigned bw_c = abits[col][quad];
    uint4    b_c[4];
    #pragma unroll
    for (int t = 0; t < 4; ++t)
        b_c[t] = *(const uint4*)(bp0 + (size_t)(t << 4) * SUPPT_LD);

    #pragma unroll 2
    for (int jl = 0; jl < JCHUNK; jl += 32) {
        const int jn = jl + 32;
        // ---- issue next step's loads (overrun on last iter is benign) ----
        const float4   fa_n = *(const float4*)(f1p + jn);
        const float4   fb_n = *(const float4*)(f1p + jn + 4);
        const unsigned bw_n = abits[col][(jn >> 3) + quad];
        uint4 b_n[4];
        #pragma unroll
        for (int t = 0; t < 4; ++t)
            b_n[t] = *(const uint4*)(bp0 + (size_t)(t << 4) * SUPPT_LD + jn);

        // ---- e-compute current (covers the in-flight loads) ----
        float e[8];
        const float fj[8] = {fa_c.x, fa_c.y, fa_c.z, fa_c.w,
                             fb_c.x, fb_c.y, fb_c.z, fb_c.w};
        #pragma unroll
        for (int jj = 0; jj < 8; ++jj) {
            const float ts = fj[jj] + f2i;
            const float lw = fmaxf(ts, NEG * ts);               // leaky
            const float a  = fmaf(lw, LOG2E, -mi1);             // log2 e^(lw-mi)
            const float ex = __builtin_amdgcn_exp2f(a);
            e[jj] = ((bw_c >> jj) & 1) ? ex : 0.f;
            lsum += e[jj];
        }
        union { short8 v; __hip_bfloat162 h2[4]; } af;
        #pragma unroll
        for (int p = 0; p < 4; ++p)
            af.h2[p] = __float22bfloat162_rn(make_float2(e[2 * p], e[2 * p + 1]));

        // ---- MFMA current ----
        #pragma unroll
        for (int t = 0; t < 4; ++t) {
            union { uint4 u; short8 s; } bb; bb.u = b_c[t];
            acc[t] = __builtin_amdgcn_mfma_f32_16x16x32_bf16(af.v, bb.s, acc[t], 0, 0, 0);
        }

        // rotate
        fa_c = fa_n; fb_c = fb_n; bw_c = bw_n;
        #pragma unroll
        for (int t = 0; t < 4; ++t) b_c[t] = b_n[t];
    }

    // partial denominator: reduce over quads, one atomic per i per wave
    lsum += __shfl_xor(lsum, 16);
    lsum += __shfl_xor(lsum, 32);   // lane L holds chunk-sum for i = L&15
    if (lane < 16) atomicAdd(&lsumg[h * N_NODES + i0 + lane], lsum);

    // partial numerator: atomicAdd in C layout (col=lane&15, row=quad*4+reg)
    #pragma unroll
    for (int reg = 0; reg < 4; ++reg) {
        const int irow = (quad << 2) + reg;
        float* op = num + (size_t)(i0 + irow) * HF + (h << 6) + col;
        #pragma unroll
        for (int t = 0; t < 4; ++t) atomicAdd(op + (t << 4), acc[t][reg]);
    }
}

// ---------------------------------------------------------------------------
// K4: out += num / lsum   (proj already sits in out from K1)
// ---------------------------------------------------------------------------
__global__ __launch_bounds__(256) void k_final(
    const float* __restrict__ num,   // [N][256]
    const float* __restrict__ lsumg, // [H][N]
    float* __restrict__ out)         // [N][256]
{
    const int idx = blockIdx.x * 256 + threadIdx.x;
    const int i = idx >> 8, c = idx & 255, h = c >> 6;
    out[idx] += num[idx] / lsumg[h * N_NODES + i];
}

// ---------------------------------------------------------------------------
extern "C" void kernel_launch(void* const* d_in, const int* in_sizes, int n_in,
                              void* d_out, int out_size, void* d_ws, size_t ws_size,
                              hipStream_t stream) {
    const float* inp  = (const float*)d_in[0];  // [8192,256]
    const float* adj  = (const float*)d_in[1];  // [8192,8192]
    const float* W    = (const float*)d_in[2];  // [256,256]
    const float* U    = (const float*)d_in[3];  // [4,64,1]
    const float* V    = (const float*)d_in[4];  // [4,64,1]
    const float* Bias = (const float*)d_in[5];  // [1,256]
    const float* PW   = (const float*)d_in[6];  // [256,256]
    const float* PB   = (const float*)d_in[7];  // [256]
    float* out = (float*)d_out;                 // [8192,256] fp32

    char* ws = (char*)d_ws;
    size_t off = 0;
    u16*   suppT = (u16*)(ws + off);   off += (size_t)HF * SUPPT_LD * 2;    // 4.21 MiB
    float* f1    = (float*)(ws + off); off += (size_t)NHEAD * N_NODES * 4;  // 128 KiB
    float* f2    = (float*)(ws + off); off += (size_t)NHEAD * N_NODES * 4;  // 128 KiB
    float* f1mx  = (float*)(ws + off); off += 256;
    float* lsumg = (float*)(ws + off); off += (size_t)NHEAD * N_NODES * 4;  // 128 KiB
    float* num   = (float*)(ws + off); off += (size_t)N_NODES * HF * 4;     // 8 MiB
    // total ws use ~12.6 MiB

    k_gemm<<<N_NODES / RPB, 256, 0, stream>>>(inp, W, U, V, Bias, PW, PB,
                                              suppT, f1, f2, out, num);
    k_f1max<<<NHEAD, 256, 0, stream>>>(f1, f1mx, lsumg);
    k_attn_mfma<<<NTILE * JC, 256, 0, stream>>>(adj, suppT, f1, f2, f1mx, num, lsumg);
    k_final<<<(N_NODES * HF) / 256, 256, 0, stream>>>(num, lsumg, out);
}